// Round 1
// baseline (22171.042 us; speedup 1.0000x reference)
//
#include <hip/hip_runtime.h>
#include <stdint.h>

#define TSEQ 1024
#define BB   32
#define DD   512
#define HH   512
#define NBLK 32
#define NTHR 384

typedef __attribute__((ext_vector_type(8))) __bf16 bf16x8;
typedef __attribute__((ext_vector_type(8))) unsigned short us8;
typedef __attribute__((ext_vector_type(4))) float f32x4;

union Frag8 { us8 u; bf16x8 b; };

__device__ __forceinline__ unsigned short f2bf(float f) {
  union { float f; unsigned u; } v; v.f = f;
  unsigned u = v.u;
  u += 0x7fffu + ((u >> 16) & 1u);   // RNE
  return (unsigned short)(u >> 16);
}

__device__ __forceinline__ float sigm(float x) {
  return 1.0f / (1.0f + __expf(-x));
}
__device__ __forceinline__ float tanh_fast(float x) {
  // stable for |x| large: exp overflow -> +-1
  return 1.0f - 2.0f / (__expf(2.0f * x) + 1.0f);
}
__device__ __forceinline__ float softplus_(float x) {
  return (x > 15.0f) ? x : log1pf(__expf(x));
}

// packed B-fragment layout: [g][n>>4 (block tile)][k>>5 (kiter)][lane][8]
// lane = kgrp*16 + n_in, so per-(tile,kiter) a wave reads 64 lanes * 16B linearly.
__device__ __forceinline__ int packidx(int g, int n, int k) {
  return ((g * 32 + (n >> 4)) * 16 + (k >> 5)) * 512 +
         (((k >> 3) & 3) * 16 + (n & 15)) * 8 + (k & 7);
}

__global__ void sample_kernel(const float* __restrict__ wih_mu, const float* __restrict__ wih_rho,
                              const float* __restrict__ whh_mu, const float* __restrict__ whh_rho,
                              const float* __restrict__ b_mu, const float* __restrict__ b_rho,
                              const float* __restrict__ eps_ih, const float* __restrict__ eps_hh,
                              const float* __restrict__ eps_b,
                              float* __restrict__ bias_s, unsigned short* __restrict__ wihp,
                              unsigned short* __restrict__ whhp) {
  int gid = blockIdx.x * 256 + threadIdx.x;
  if (gid >= 512 * 2048) return;
  int k = gid >> 11, col = gid & 2047;
  // w_ih: only cols [0,3H) used; gates r(0:512) z(512:1024) n(1024:1536)
  if (col < 1536) {
    float w = wih_mu[gid] + softplus_(wih_rho[gid]) * eps_ih[gid];
    wihp[packidx(col >> 9, col & 511, k)] = f2bf(w);
  }
  // w_hh: cols [0,2H) are r,z ; cols [3H,4H) are n-gate
  {
    int g = -1, n = 0;
    if (col < 1024) { g = col >> 9; n = col & 511; }
    else if (col >= 1536) { g = 2; n = col - 1536; }
    if (g >= 0) {
      float w = whh_mu[gid] + softplus_(whh_rho[gid]) * eps_hh[gid];
      whhp[packidx(g, n, k)] = f2bf(w);
    }
  }
  if (gid < 2048) bias_s[gid] = b_mu[gid] + softplus_(b_rho[gid]) * eps_b[gid];
}

// Persistent scan kernel: 32 blocks (block bid owns h cols [bid*16, bid*16+16)),
// 6 waves = (gate r/z/n) x (m-half). W_hh fragments live in VGPRs for all 1024 steps.
// h exchanged via packed-bf16 global double buffer; fp32 carried state in registers.
__global__ __launch_bounds__(NTHR, 2) void gru_scan(
    const float* __restrict__ x, const float* __restrict__ h0,
    const float* __restrict__ bias_s,
    const unsigned short* __restrict__ wihp, const unsigned short* __restrict__ whhp,
    unsigned short* __restrict__ hb, unsigned* __restrict__ flags,
    float* __restrict__ out)
{
  __shared__ __align__(16) unsigned short hp[16384];  // packed h(t) bf16, 32KB
  __shared__ float Ar[32][17];
  __shared__ float Az[32][17];
  __shared__ float P1[32][17];  // xg n-part
  __shared__ float P2[32][17];  // rec n-part

  const int tid = threadIdx.x;
  const int bid = blockIdx.x;
  const int lane = tid & 63;
  const int wave = tid >> 6;      // 0..5
  const int g = wave >> 1;        // gate 0=r 1=z 2=n
  const int mh = wave & 1;        // m half (batch rows 0:16 / 16:32)
  const int l15 = lane & 15;
  const int lq = lane >> 4;       // kgrp (A/B) == row quad (C/D)
  const int c0 = bid * 16;

  // element mapping for the activation stage: e1 = tid, e2 = tid+384
  const int jj = tid & 15;
  const int m1 = tid >> 4;        // 0..23
  const int m2 = m1 + 24;         // 24..31 valid iff tid<128
  const float b_r  = bias_s[c0 + jj];
  const float b_z  = bias_s[512 + c0 + jj];
  const float b_n  = bias_s[1024 + c0 + jj];
  const float b_hn = bias_s[1536 + c0 + jj];
  float hold1 = h0[m1 * HH + c0 + jj];
  float hold2 = (tid < 128) ? h0[m2 * HH + c0 + jj] : 0.0f;

  // preload W_hh B-fragments: 16 kiter x 16B/lane = 64 VGPRs, kept for whole kernel
  Frag8 wreg[16];
  {
    const unsigned short* wb = whhp + (size_t)((g * 32 + bid) * 16) * 512 + lane * 8;
#pragma unroll
    for (int ki = 0; ki < 16; ki++) wreg[ki].u = *(const us8*)(wb + ki * 512);
  }

  const unsigned short* wib = wihp + (size_t)((g * 32 + bid) * 16) * 512 + lane * 8;
  const int xrow = mh * 16 + l15;  // batch row for A fragments

  f32x4 xacc;
  // prologue: xg for t=0
  {
    f32x4 acc = {0.f, 0.f, 0.f, 0.f};
    const float* xs = x + (size_t)xrow * TSEQ * DD + lq * 8;
#pragma unroll
    for (int ki = 0; ki < 16; ki++) {
      f32x4 x0 = *(const f32x4*)(xs + ki * 32);
      f32x4 x1 = *(const f32x4*)(xs + ki * 32 + 4);
      Frag8 a;
#pragma unroll
      for (int j = 0; j < 4; j++) { a.u[j] = f2bf(x0[j]); a.u[4 + j] = f2bf(x1[j]); }
      Frag8 b; b.u = *(const us8*)(wib + ki * 512);
      acc = __builtin_amdgcn_mfma_f32_16x16x32_bf16(a.b, b.b, acc, 0, 0, 0);
    }
    xacc = acc;
  }

  for (int t = 0; t < TSEQ; t++) {
    // ---- phase 1: stage h(t) -> LDS (packed A-fragment order) ----
    if (t == 0) {
      for (int c = tid; c < 2048; c += NTHR) {
        int m = c & 31, kg = (c >> 5) & 3, ki = c >> 7;
        const float* s = h0 + m * HH + ki * 32 + kg * 8;
        us8 v;
#pragma unroll
        for (int j = 0; j < 8; j++) v[j] = f2bf(s[j]);
        *(us8*)(hp + c * 8) = v;
      }
    } else {
      const unsigned short* src = hb + (t & 1) * 16384;
      for (int c = tid; c < 2048; c += NTHR)
        *(us8*)(hp + c * 8) = *(const us8*)(src + c * 8);
    }
    __syncthreads();

    // ---- phase 2: recurrent matmul (B-frags already in registers) ----
    f32x4 rec = {0.f, 0.f, 0.f, 0.f};
    {
      const unsigned short* hpp = hp + lq * 256 + (mh * 16 + l15) * 8;
#pragma unroll
      for (int ki = 0; ki < 16; ki++) {
        Frag8 a; a.u = *(const us8*)(hpp + ki * 1024);
        rec = __builtin_amdgcn_mfma_f32_16x16x32_bf16(a.b, wreg[ki].b, rec, 0, 0, 0);
      }
    }

    // ---- phase 3: publish pre-activations (C layout: col=l&15, row=lq*4+r) ----
#pragma unroll
    for (int r = 0; r < 4; r++) {
      int m = mh * 16 + lq * 4 + r;
      if (g == 0)      Ar[m][l15] = xacc[r] + rec[r];
      else if (g == 1) Az[m][l15] = xacc[r] + rec[r];
      else             { P1[m][l15] = xacc[r]; P2[m][l15] = rec[r]; }
    }
    __syncthreads();

    // ---- phase 4: gates + state update; write outputs ----
    unsigned short* hbdst = hb + ((t + 1) & 1) * 16384;
    {
      float r1 = sigm(Ar[m1][jj] + b_r);
      float z1 = sigm(Az[m1][jj] + b_z);
      float n1 = tanh_fast(P1[m1][jj] + b_n + r1 * (P2[m1][jj] + b_hn));
      float h1 = (1.f - z1) * n1 + z1 * hold1;
      hold1 = h1;
      int k = c0 + jj;
      out[(size_t)m1 * (TSEQ * HH) + (size_t)t * HH + k] = h1;
      hbdst[(k >> 5) * 1024 + ((k >> 3) & 3) * 256 + m1 * 8 + (k & 7)] = f2bf(h1);
      if (t == TSEQ - 1) out[(size_t)BB * TSEQ * HH + m1 * HH + k] = h1;
    }
    if (tid < 128) {
      float r1 = sigm(Ar[m2][jj] + b_r);
      float z1 = sigm(Az[m2][jj] + b_z);
      float n1 = tanh_fast(P1[m2][jj] + b_n + r1 * (P2[m2][jj] + b_hn));
      float h1 = (1.f - z1) * n1 + z1 * hold2;
      hold2 = h1;
      int k = c0 + jj;
      out[(size_t)m2 * (TSEQ * HH) + (size_t)t * HH + k] = h1;
      hbdst[(k >> 5) * 1024 + ((k >> 3) & 3) * 256 + m2 * 8 + (k & 7)] = f2bf(h1);
      if (t == TSEQ - 1) out[(size_t)BB * TSEQ * HH + m2 * HH + k] = h1;
    }
    __threadfence();            // release: h writes visible at agent scope
    __syncthreads();
    if (tid == 0)
      __hip_atomic_store(&flags[bid], (unsigned)(t + 1), __ATOMIC_RELEASE, __HIP_MEMORY_SCOPE_AGENT);

    // ---- phase 5: xg(t+1), overlapped with other blocks finishing step t ----
    if (t + 1 < TSEQ) {
      f32x4 acc = {0.f, 0.f, 0.f, 0.f};
      const float* xs = x + ((size_t)xrow * TSEQ + (t + 1)) * DD + lq * 8;
#pragma unroll
      for (int ki = 0; ki < 16; ki++) {
        f32x4 x0 = *(const f32x4*)(xs + ki * 32);
        f32x4 x1 = *(const f32x4*)(xs + ki * 32 + 4);
        Frag8 a;
#pragma unroll
        for (int j = 0; j < 4; j++) { a.u[j] = f2bf(x0[j]); a.u[4 + j] = f2bf(x1[j]); }
        Frag8 b; b.u = *(const us8*)(wib + ki * 512);
        acc = __builtin_amdgcn_mfma_f32_16x16x32_bf16(a.b, b.b, acc, 0, 0, 0);
      }
      xacc = acc;
    }

    // ---- phase 6: device-wide barrier (monotonic flags, agent scope) ----
    if (tid < 64) {
      unsigned tgt = (unsigned)(t + 1);
      if (lane < NBLK) {
        while (__hip_atomic_load(&flags[lane], __ATOMIC_RELAXED, __HIP_MEMORY_SCOPE_AGENT) < tgt)
          __builtin_amdgcn_s_sleep(4);
      }
    }
    __syncthreads();
    __threadfence();            // acquire: invalidate L1 before reading hb next iter
  }
}

extern "C" void kernel_launch(void* const* d_in, const int* in_sizes, int n_in,
                              void* d_out, int out_size, void* d_ws, size_t ws_size,
                              hipStream_t stream) {
  const float* x       = (const float*)d_in[0];
  const float* h0      = (const float*)d_in[1];
  const float* wih_mu  = (const float*)d_in[2];
  const float* wih_rho = (const float*)d_in[3];
  const float* whh_mu  = (const float*)d_in[4];
  const float* whh_rho = (const float*)d_in[5];
  const float* b_mu    = (const float*)d_in[6];
  const float* b_rho   = (const float*)d_in[7];
  const float* eps_ih  = (const float*)d_in[8];
  const float* eps_hh  = (const float*)d_in[9];
  const float* eps_b   = (const float*)d_in[10];

  uint8_t* ws = (uint8_t*)d_ws;
  unsigned* flags       = (unsigned*)ws;                              // 128B used
  float* bias_s         = (float*)(ws + 4096);                        // 8KB
  unsigned short* wihp  = (unsigned short*)(ws + 16384);              // 1.5MB
  unsigned short* whhp  = (unsigned short*)(ws + 16384 + (1u << 21)); // 1.5MB
  unsigned short* hb    = (unsigned short*)(ws + 16384 + (2u << 21)); // 2 x 32KB

  hipMemsetAsync(flags, 0, 256, stream);
  sample_kernel<<<4096, 256, 0, stream>>>(wih_mu, wih_rho, whh_mu, whh_rho,
                                          b_mu, b_rho, eps_ih, eps_hh, eps_b,
                                          bias_s, wihp, whhp);
  gru_scan<<<NBLK, NTHR, 0, stream>>>(x, h0, bias_s, wihp, whhp, hb, flags, (float*)d_out);
}

// Round 2
// 16224.925 us; speedup vs baseline: 1.3665x; 1.3665x over previous
//
#include <hip/hip_runtime.h>
#include <stdint.h>

#define TSEQ 1024
#define BB   32
#define DD   512
#define HH   512
#define NBLK 32
#define NTHR 384

typedef __attribute__((ext_vector_type(8))) __bf16 bf16x8;
typedef __attribute__((ext_vector_type(8))) unsigned short us8;
typedef __attribute__((ext_vector_type(4))) float f32x4;
typedef __attribute__((ext_vector_type(2))) float f32x2;

union Frag8 { us8 u; bf16x8 b; };

__device__ __forceinline__ unsigned short f2bf(float f) {
  union { float f; unsigned u; } v; v.f = f;
  unsigned u = v.u;
  u += 0x7fffu + ((u >> 16) & 1u);   // RNE
  return (unsigned short)(u >> 16);
}

__device__ __forceinline__ float sigm(float x) {
  return 1.0f / (1.0f + __expf(-x));
}
__device__ __forceinline__ float tanh_fast(float x) {
  return 1.0f - 2.0f / (__expf(2.0f * x) + 1.0f);
}
__device__ __forceinline__ float softplus_(float x) {
  return (x > 15.0f) ? x : log1pf(__expf(x));
}

// packed B-fragment layout: [g][n>>4 (block tile)][k>>5 (kiter)][lane][8]
__device__ __forceinline__ int packidx(int g, int n, int k) {
  return ((g * 32 + (n >> 4)) * 16 + (k >> 5)) * 512 +
         (((k >> 3) & 3) * 16 + (n & 15)) * 8 + (k & 7);
}
// packed h layout (A-fragment order): idx = (k>>5)*1024 + ((k>>3)&3)*256 + m*8 + (k&7)
__device__ __forceinline__ int hidx(int m, int k) {
  return (k >> 5) * 1024 + ((k >> 3) & 3) * 256 + m * 8 + (k & 7);
}

__global__ void sample_kernel(const float* __restrict__ wih_mu, const float* __restrict__ wih_rho,
                              const float* __restrict__ whh_mu, const float* __restrict__ whh_rho,
                              const float* __restrict__ b_mu, const float* __restrict__ b_rho,
                              const float* __restrict__ eps_ih, const float* __restrict__ eps_hh,
                              const float* __restrict__ eps_b, const float* __restrict__ h0,
                              float* __restrict__ bias_s, unsigned short* __restrict__ wihp,
                              unsigned short* __restrict__ whhp, unsigned short* __restrict__ hb) {
  int gid = blockIdx.x * 256 + threadIdx.x;
  if (gid >= 512 * 2048) return;
  int k = gid >> 11, col = gid & 2047;
  if (col < 1536) {
    float w = wih_mu[gid] + softplus_(wih_rho[gid]) * eps_ih[gid];
    wihp[packidx(col >> 9, col & 511, k)] = f2bf(w);
  }
  {
    int g = -1, n = 0;
    if (col < 1024) { g = col >> 9; n = col & 511; }
    else if (col >= 1536) { g = 2; n = col - 1536; }
    if (g >= 0) {
      float w = whh_mu[gid] + softplus_(whh_rho[gid]) * eps_hh[gid];
      whhp[packidx(g, n, k)] = f2bf(w);
    }
  }
  if (gid < 2048) bias_s[gid] = b_mu[gid] + softplus_(b_rho[gid]) * eps_b[gid];
  // pre-pack h0 -> hb buffer 0 (kernel-boundary flush makes this visible device-wide)
  if (gid < BB * HH) {
    int m = gid >> 9, kk = gid & 511;
    hb[hidx(m, kk)] = f2bf(h0[gid]);
  }
}

// Persistent scan: 32 blocks x 384 threads; block bid owns h cols [bid*16, bid*16+16).
// W_hh fragments in VGPRs for all 1024 steps. h exchanged via packed-bf16 global
// double buffer written with sc1 (agent-scope relaxed atomic stores) -> coherent at L3;
// no release fence / L2 writeback on the critical path. One acquire buffer_inv per step.
__global__ __launch_bounds__(NTHR, 2) void gru_scan(
    const float* __restrict__ x, const float* __restrict__ h0,
    const float* __restrict__ bias_s,
    const unsigned short* __restrict__ wihp, const unsigned short* __restrict__ whhp,
    unsigned short* __restrict__ hb, unsigned* __restrict__ flags,
    float* __restrict__ out)
{
  __shared__ float Ar[32][17];
  __shared__ float Az[32][17];
  __shared__ float P1[32][17];  // xg n-part
  __shared__ float P2[32][17];  // rec n-part

  const int tid = threadIdx.x;
  const int bid = blockIdx.x;
  const int lane = tid & 63;
  const int wave = tid >> 6;      // 0..5
  const int g = wave >> 1;        // gate 0=r 1=z 2=n
  const int mh = wave & 1;        // m half
  const int l15 = lane & 15;
  const int lq = lane >> 4;       // k-group (A/B) == row quad (C/D)
  const int c0 = bid * 16;

  // epilogue mapping: 256 threads, each handles (m, 2 adjacent cols)
  const int em = tid >> 3;        // 0..31 (valid for tid<256)
  const int ejp = (tid & 7) * 2;  // col pair base within the 16-col tile
  float b_r[2], b_z[2], b_n[2], b_hn[2], hold[2];
  if (tid < 256) {
#pragma unroll
    for (int e = 0; e < 2; e++) {
      int k = c0 + ejp + e;
      b_r[e]  = bias_s[k];
      b_z[e]  = bias_s[512 + k];
      b_n[e]  = bias_s[1024 + k];
      b_hn[e] = bias_s[1536 + k];
      hold[e] = h0[em * HH + k];
    }
  }

  // preload W_hh B-fragments (64 VGPRs, resident for whole kernel)
  Frag8 wreg[16];
  {
    const unsigned short* wb = whhp + (size_t)((g * 32 + bid) * 16) * 512 + lane * 8;
#pragma unroll
    for (int ki = 0; ki < 16; ki++) wreg[ki].u = *(const us8*)(wb + ki * 512);
  }

  const unsigned short* wib = wihp + (size_t)((g * 32 + bid) * 16) * 512 + lane * 8;
  const int xrow = mh * 16 + l15;

  f32x4 xacc;
  { // prologue: xg for t=0
    f32x4 acc = {0.f, 0.f, 0.f, 0.f};
    const float* xs = x + (size_t)xrow * TSEQ * DD + lq * 8;
#pragma unroll
    for (int ki = 0; ki < 16; ki++) {
      f32x4 x0 = *(const f32x4*)(xs + ki * 32);
      f32x4 x1 = *(const f32x4*)(xs + ki * 32 + 4);
      Frag8 a;
#pragma unroll
      for (int j = 0; j < 4; j++) { a.u[j] = f2bf(x0[j]); a.u[4 + j] = f2bf(x1[j]); }
      Frag8 b; b.u = *(const us8*)(wib + ki * 512);
      acc = __builtin_amdgcn_mfma_f32_16x16x32_bf16(a.b, b.b, acc, 0, 0, 0);
    }
    xacc = acc;
  }

  for (int t = 0; t < TSEQ; t++) {
    // ---- phase 1+2: recurrent matmul, A-frags straight from global hb ----
    f32x4 rec = {0.f, 0.f, 0.f, 0.f};
    {
      const unsigned short* src = hb + (t & 1) * 16384 + lq * 256 + (mh * 16 + l15) * 8;
#pragma unroll
      for (int ki = 0; ki < 16; ki++) {
        Frag8 a; a.u = *(const us8*)(src + ki * 1024);
        rec = __builtin_amdgcn_mfma_f32_16x16x32_bf16(a.b, wreg[ki].b, rec, 0, 0, 0);
      }
    }

    // ---- phase 3: publish pre-activations (C layout: col=l&15, row=lq*4+r) ----
#pragma unroll
    for (int r = 0; r < 4; r++) {
      int m = mh * 16 + lq * 4 + r;
      if (g == 0)      Ar[m][l15] = xacc[r] + rec[r];
      else if (g == 1) Az[m][l15] = xacc[r] + rec[r];
      else             { P1[m][l15] = xacc[r]; P2[m][l15] = rec[r]; }
    }
    __syncthreads();

    // ---- phase 4: gates + state update (256 threads, col pairs) ----
    if (tid < 256) {
      unsigned short* hbdst = hb + ((t + 1) & 1) * 16384;
      float hn[2];
#pragma unroll
      for (int e = 0; e < 2; e++) {
        int j = ejp + e;
        float r1 = sigm(Ar[em][j] + b_r[e]);
        float z1 = sigm(Az[em][j] + b_z[e]);
        float n1 = tanh_fast(P1[em][j] + b_n[e] + r1 * (P2[em][j] + b_hn[e]));
        hn[e] = (1.f - z1) * n1 + z1 * hold[e];
        hold[e] = hn[e];
      }
      int k0 = c0 + ejp;
      f32x2 ov; ov[0] = hn[0]; ov[1] = hn[1];
      *(f32x2*)(out + (size_t)em * (TSEQ * HH) + (size_t)t * HH + k0) = ov;
      if (t == TSEQ - 1)
        *(f32x2*)(out + (size_t)BB * TSEQ * HH + em * HH + k0) = ov;
      unsigned packed = (unsigned)f2bf(hn[0]) | ((unsigned)f2bf(hn[1]) << 16);
      // sc1 write-through to L3 (agent coherence point) -> no release fence needed
      __hip_atomic_store((unsigned*)(hbdst + hidx(em, k0)), packed,
                         __ATOMIC_RELAXED, __HIP_MEMORY_SCOPE_AGENT);
    }
    __syncthreads();  // pre-barrier vmcnt(0) drains the sc1 stores of every wave
    if (tid == 0)
      __hip_atomic_store(&flags[bid], (unsigned)(t + 1),
                         __ATOMIC_RELAXED, __HIP_MEMORY_SCOPE_AGENT);

    // ---- phase 5: xg(t+1), overlapped with other blocks finishing step t ----
    if (t + 1 < TSEQ) {
      f32x4 acc = {0.f, 0.f, 0.f, 0.f};
      const float* xs = x + ((size_t)xrow * TSEQ + (t + 1)) * DD + lq * 8;
#pragma unroll
      for (int ki = 0; ki < 16; ki++) {
        f32x4 x0 = *(const f32x4*)(xs + ki * 32);
        f32x4 x1 = *(const f32x4*)(xs + ki * 32 + 4);
        Frag8 a;
#pragma unroll
        for (int j = 0; j < 4; j++) { a.u[j] = f2bf(x0[j]); a.u[4 + j] = f2bf(x1[j]); }
        Frag8 b; b.u = *(const us8*)(wib + ki * 512);
        acc = __builtin_amdgcn_mfma_f32_16x16x32_bf16(a.b, b.b, acc, 0, 0, 0);
      }
      xacc = acc;

      // ---- phase 6: device-wide barrier ----
      if (tid < 64 && lane < NBLK) {
        unsigned tgt = (unsigned)(t + 1);
        while (__hip_atomic_load(&flags[lane], __ATOMIC_RELAXED,
                                 __HIP_MEMORY_SCOPE_AGENT) < tgt)
          __builtin_amdgcn_s_sleep(1);
      }
      __syncthreads();
      // acquire: waitcnt + buffer_inv (no L2 writeback) so next hb reads are fresh
      __builtin_amdgcn_fence(__ATOMIC_ACQUIRE, "agent");
    }
  }
}

extern "C" void kernel_launch(void* const* d_in, const int* in_sizes, int n_in,
                              void* d_out, int out_size, void* d_ws, size_t ws_size,
                              hipStream_t stream) {
  const float* x       = (const float*)d_in[0];
  const float* h0      = (const float*)d_in[1];
  const float* wih_mu  = (const float*)d_in[2];
  const float* wih_rho = (const float*)d_in[3];
  const float* whh_mu  = (const float*)d_in[4];
  const float* whh_rho = (const float*)d_in[5];
  const float* b_mu    = (const float*)d_in[6];
  const float* b_rho   = (const float*)d_in[7];
  const float* eps_ih  = (const float*)d_in[8];
  const float* eps_hh  = (const float*)d_in[9];
  const float* eps_b   = (const float*)d_in[10];

  uint8_t* ws = (uint8_t*)d_ws;
  unsigned* flags       = (unsigned*)ws;                              // 128B used
  float* bias_s         = (float*)(ws + 4096);                        // 8KB
  unsigned short* wihp  = (unsigned short*)(ws + 16384);              // 1.5MB
  unsigned short* whhp  = (unsigned short*)(ws + 16384 + (1u << 21)); // 1.5MB
  unsigned short* hb    = (unsigned short*)(ws + 16384 + (2u << 21)); // 2 x 32KB

  hipMemsetAsync(flags, 0, 256, stream);
  sample_kernel<<<4096, 256, 0, stream>>>(wih_mu, wih_rho, whh_mu, whh_rho,
                                          b_mu, b_rho, eps_ih, eps_hh, eps_b, h0,
                                          bias_s, wihp, whhp, hb);
  gru_scan<<<NBLK, NTHR, 0, stream>>>(x, h0, bias_s, wihp, whhp, hb, flags, (float*)d_out);
}

// Round 3
// 8588.950 us; speedup vs baseline: 2.5813x; 1.8890x over previous
//
#include <hip/hip_runtime.h>
#include <stdint.h>

#define TSEQ 1024
#define BB   32
#define DD   512
#define HH   512
#define NBLK 32
#define NTHR 384

typedef __attribute__((ext_vector_type(8))) __bf16 bf16x8;
typedef __attribute__((ext_vector_type(8))) unsigned short us8;
typedef __attribute__((ext_vector_type(4))) float f32x4;
typedef __attribute__((ext_vector_type(2))) float f32x2;
typedef __attribute__((ext_vector_type(4))) int i32x4;

union Frag8 { us8 u; bf16x8 b; };
union FragA { i32x4 i; bf16x8 b; };

__device__ __forceinline__ unsigned short f2bf(float f) {
  union { float f; unsigned u; } v; v.f = f;
  unsigned u = v.u;
  u += 0x7fffu + ((u >> 16) & 1u);   // RNE
  return (unsigned short)(u >> 16);
}

__device__ __forceinline__ float sigm(float x) {
  return 1.0f / (1.0f + __expf(-x));
}
__device__ __forceinline__ float tanh_fast(float x) {
  return 1.0f - 2.0f / (__expf(2.0f * x) + 1.0f);
}
__device__ __forceinline__ float softplus_(float x) {
  return (x > 15.0f) ? x : log1pf(__expf(x));
}

// packed B-fragment layout: [g][n>>4 (block tile)][k>>5 (kiter)][lane][8]
__device__ __forceinline__ int packidx(int g, int n, int k) {
  return ((g * 32 + (n >> 4)) * 16 + (k >> 5)) * 512 +
         (((k >> 3) & 3) * 16 + (n & 15)) * 8 + (k & 7);
}
// packed h layout (A-fragment order)
__device__ __forceinline__ int hidx(int m, int k) {
  return (k >> 5) * 1024 + ((k >> 3) & 3) * 256 + m * 8 + (k & 7);
}

__global__ void sample_kernel(const float* __restrict__ wih_mu, const float* __restrict__ wih_rho,
                              const float* __restrict__ whh_mu, const float* __restrict__ whh_rho,
                              const float* __restrict__ b_mu, const float* __restrict__ b_rho,
                              const float* __restrict__ eps_ih, const float* __restrict__ eps_hh,
                              const float* __restrict__ eps_b, const float* __restrict__ h0,
                              float* __restrict__ bias_s, unsigned short* __restrict__ wihp,
                              unsigned short* __restrict__ whhp, unsigned short* __restrict__ hb) {
  int gid = blockIdx.x * 256 + threadIdx.x;
  if (gid >= 512 * 2048) return;
  int k = gid >> 11, col = gid & 2047;
  if (col < 1536) {
    float w = wih_mu[gid] + softplus_(wih_rho[gid]) * eps_ih[gid];
    wihp[packidx(col >> 9, col & 511, k)] = f2bf(w);
  }
  {
    int g = -1, n = 0;
    if (col < 1024) { g = col >> 9; n = col & 511; }
    else if (col >= 1536) { g = 2; n = col - 1536; }
    if (g >= 0) {
      float w = whh_mu[gid] + softplus_(whh_rho[gid]) * eps_hh[gid];
      whhp[packidx(g, n, k)] = f2bf(w);
    }
  }
  if (gid < 2048) bias_s[gid] = b_mu[gid] + softplus_(b_rho[gid]) * eps_b[gid];
  // pre-pack h0 -> hb buffer 0 (end-of-kernel writeback makes this L3-visible)
  if (gid < BB * HH) {
    int m = gid >> 9, kk = gid & 511;
    hb[hidx(m, kk)] = f2bf(h0[gid]);
  }
}

// Persistent scan: 32 blocks x 384 threads; block bid owns h cols [bid*16, bid*16+16).
// NO cache-maintenance on the critical path: hb is written with sc1 (write-through
// to L3, the agent coherence point) and read with explicit sc1 loads (bypass L1/L2,
// read L3 directly). x/weights stay warm in L1/L2 across steps.
__global__ __launch_bounds__(NTHR, 1) void gru_scan(
    const float* __restrict__ x, const float* __restrict__ h0,
    const float* __restrict__ bias_s,
    const unsigned short* __restrict__ wihp, const unsigned short* __restrict__ whhp,
    unsigned short* __restrict__ hb, unsigned* __restrict__ flags,
    float* __restrict__ out)
{
  __shared__ float Ar[32][17];
  __shared__ float Az[32][17];
  __shared__ float P1[32][17];  // xg n-part
  __shared__ float P2[32][17];  // rec n-part

  const int tid = threadIdx.x;
  const int bid = blockIdx.x;
  const int lane = tid & 63;
  const int wave = tid >> 6;      // 0..5
  const int g = wave >> 1;        // gate 0=r 1=z 2=n
  const int mh = wave & 1;        // m half
  const int l15 = lane & 15;
  const int lq = lane >> 4;       // k-group (A/B) == row quad (C/D)
  const int c0 = bid * 16;

  // epilogue mapping: 256 threads, each handles (m, 2 adjacent cols)
  const int em = tid >> 3;        // 0..31 (valid for tid<256)
  const int ejp = (tid & 7) * 2;
  const bool active = tid < 256;
  float b_r[2], b_z[2], b_n[2], b_hn[2], hold[2];
  if (active) {
#pragma unroll
    for (int e = 0; e < 2; e++) {
      int k = c0 + ejp + e;
      b_r[e]  = bias_s[k];
      b_z[e]  = bias_s[512 + k];
      b_n[e]  = bias_s[1024 + k];
      b_hn[e] = bias_s[1536 + k];
      hold[e] = h0[em * HH + k];
    }
  }

  // preload W_hh B-fragments (64 VGPRs, resident for whole kernel)
  Frag8 wreg[16];
  {
    const unsigned short* wb = whhp + (size_t)((g * 32 + bid) * 16) * 512 + lane * 8;
#pragma unroll
    for (int ki = 0; ki < 16; ki++) wreg[ki].u = *(const us8*)(wb + ki * 512);
  }

  const unsigned short* wib = wihp + (size_t)((g * 32 + bid) * 16) * 512 + lane * 8;
  const int xrow = mh * 16 + l15;

  f32x4 xacc;
  { // prologue: xg for t=0
    f32x4 a0 = {0.f, 0.f, 0.f, 0.f}, a1 = {0.f, 0.f, 0.f, 0.f};
    const float* xs = x + (size_t)xrow * TSEQ * DD + lq * 8;
#pragma unroll
    for (int ki = 0; ki < 16; ki++) {
      f32x4 x0 = *(const f32x4*)(xs + ki * 32);
      f32x4 x1 = *(const f32x4*)(xs + ki * 32 + 4);
      Frag8 a;
#pragma unroll
      for (int j = 0; j < 4; j++) { a.u[j] = f2bf(x0[j]); a.u[4 + j] = f2bf(x1[j]); }
      Frag8 b; b.u = *(const us8*)(wib + ki * 512);
      if (ki & 1) a1 = __builtin_amdgcn_mfma_f32_16x16x32_bf16(a.b, b.b, a1, 0, 0, 0);
      else        a0 = __builtin_amdgcn_mfma_f32_16x16x32_bf16(a.b, b.b, a0, 0, 0, 0);
    }
    xacc = a0 + a1;
  }

  for (int t = 0; t < TSEQ; t++) {
    // ---- phase A: recurrent matmul; A-frags via sc1 loads straight from L3 ----
    FragA af[16];
    {
      const unsigned short* src = hb + (t & 1) * 16384 + lq * 256 + (mh * 16 + l15) * 8;
#pragma unroll
      for (int ki = 0; ki < 16; ki++)
        asm volatile("global_load_dwordx4 %0, %1, off sc1"
                     : "=&v"(af[ki].i) : "v"(src + ki * 1024));
      asm volatile("s_waitcnt vmcnt(0)"
                   : "+v"(af[0].i), "+v"(af[1].i), "+v"(af[2].i), "+v"(af[3].i),
                     "+v"(af[4].i), "+v"(af[5].i), "+v"(af[6].i), "+v"(af[7].i),
                     "+v"(af[8].i), "+v"(af[9].i), "+v"(af[10].i), "+v"(af[11].i),
                     "+v"(af[12].i), "+v"(af[13].i), "+v"(af[14].i), "+v"(af[15].i)
                   :
                   : "memory");
    }
    f32x4 rec0 = {0.f, 0.f, 0.f, 0.f}, rec1 = {0.f, 0.f, 0.f, 0.f};
#pragma unroll
    for (int ki = 0; ki < 8; ki++) {
      rec0 = __builtin_amdgcn_mfma_f32_16x16x32_bf16(af[ki].b,     wreg[ki].b,     rec0, 0, 0, 0);
      rec1 = __builtin_amdgcn_mfma_f32_16x16x32_bf16(af[ki + 8].b, wreg[ki + 8].b, rec1, 0, 0, 0);
    }
    f32x4 rec = rec0 + rec1;

    // ---- phase B: publish pre-activations (C layout: col=l&15, row=lq*4+r) ----
#pragma unroll
    for (int r = 0; r < 4; r++) {
      int m = mh * 16 + lq * 4 + r;
      if (g == 0)      Ar[m][l15] = xacc[r] + rec[r];
      else if (g == 1) Az[m][l15] = xacc[r] + rec[r];
      else             { P1[m][l15] = xacc[r]; P2[m][l15] = rec[r]; }
    }
    __syncthreads();

    // ---- phase C: gates + state update; hb sc1 store only (out deferred) ----
    float hn[2];
    if (active) {
#pragma unroll
      for (int e = 0; e < 2; e++) {
        int j = ejp + e;
        float r1 = sigm(Ar[em][j] + b_r[e]);
        float z1 = sigm(Az[em][j] + b_z[e]);
        float n1 = tanh_fast(P1[em][j] + b_n[e] + r1 * (P2[em][j] + b_hn[e]));
        hn[e] = (1.f - z1) * n1 + z1 * hold[e];
        hold[e] = hn[e];
      }
      unsigned short* hbdst = hb + ((t + 1) & 1) * 16384;
      unsigned packed = (unsigned)f2bf(hn[0]) | ((unsigned)f2bf(hn[1]) << 16);
      __hip_atomic_store((unsigned*)(hbdst + hidx(em, c0 + ejp)), packed,
                         __ATOMIC_RELAXED, __HIP_MEMORY_SCOPE_AGENT);
    }
    // ---- phase D: barrier drains the sc1 stores (vmcnt(0) before s_barrier) ----
    __syncthreads();
    // ---- phase E: post flag ----
    if (tid == 0)
      __hip_atomic_store(&flags[bid], (unsigned)(t + 1),
                         __ATOMIC_RELAXED, __HIP_MEMORY_SCOPE_AGENT);

    // ---- phase F: out stores, off the release path ----
    if (active) {
      int k0 = c0 + ejp;
      f32x2 ov; ov[0] = hn[0]; ov[1] = hn[1];
      *(f32x2*)(out + (size_t)em * (TSEQ * HH) + (size_t)t * HH + k0) = ov;
      if (t == TSEQ - 1)
        *(f32x2*)(out + (size_t)BB * TSEQ * HH + em * HH + k0) = ov;
    }

    if (t + 1 < TSEQ) {
      // ---- phase G: xg(t+1), overlapped with other blocks finishing step t ----
      f32x4 a0 = {0.f, 0.f, 0.f, 0.f}, a1 = {0.f, 0.f, 0.f, 0.f};
      const float* xs = x + ((size_t)xrow * TSEQ + (t + 1)) * DD + lq * 8;
#pragma unroll
      for (int ki = 0; ki < 16; ki++) {
        f32x4 x0 = *(const f32x4*)(xs + ki * 32);
        f32x4 x1 = *(const f32x4*)(xs + ki * 32 + 4);
        Frag8 a;
#pragma unroll
        for (int j = 0; j < 4; j++) { a.u[j] = f2bf(x0[j]); a.u[4 + j] = f2bf(x1[j]); }
        Frag8 b; b.u = *(const us8*)(wib + ki * 512);
        if (ki & 1) a1 = __builtin_amdgcn_mfma_f32_16x16x32_bf16(a.b, b.b, a1, 0, 0, 0);
        else        a0 = __builtin_amdgcn_mfma_f32_16x16x32_bf16(a.b, b.b, a0, 0, 0, 0);
      }
      xacc = a0 + a1;

      // ---- phase H: device-wide barrier (no sleep, no fence) ----
      if (wave == 0 && lane < NBLK) {
        unsigned tgt = (unsigned)(t + 1);
        while (__hip_atomic_load(&flags[lane], __ATOMIC_RELAXED,
                                 __HIP_MEMORY_SCOPE_AGENT) < tgt) { }
      }
      __syncthreads();
    }
  }
}

extern "C" void kernel_launch(void* const* d_in, const int* in_sizes, int n_in,
                              void* d_out, int out_size, void* d_ws, size_t ws_size,
                              hipStream_t stream) {
  const float* x       = (const float*)d_in[0];
  const float* h0      = (const float*)d_in[1];
  const float* wih_mu  = (const float*)d_in[2];
  const float* wih_rho = (const float*)d_in[3];
  const float* whh_mu  = (const float*)d_in[4];
  const float* whh_rho = (const float*)d_in[5];
  const float* b_mu    = (const float*)d_in[6];
  const float* b_rho   = (const float*)d_in[7];
  const float* eps_ih  = (const float*)d_in[8];
  const float* eps_hh  = (const float*)d_in[9];
  const float* eps_b   = (const float*)d_in[10];

  uint8_t* ws = (uint8_t*)d_ws;
  unsigned* flags       = (unsigned*)ws;                              // 128B used
  float* bias_s         = (float*)(ws + 4096);                        // 8KB
  unsigned short* wihp  = (unsigned short*)(ws + 16384);              // 1.5MB
  unsigned short* whhp  = (unsigned short*)(ws + 16384 + (1u << 21)); // 1.5MB
  unsigned short* hb    = (unsigned short*)(ws + 16384 + (2u << 21)); // 2 x 32KB

  hipMemsetAsync(flags, 0, 256, stream);
  sample_kernel<<<4096, 256, 0, stream>>>(wih_mu, wih_rho, whh_mu, whh_rho,
                                          b_mu, b_rho, eps_ih, eps_hh, eps_b, h0,
                                          bias_s, wihp, whhp, hb);
  gru_scan<<<NBLK, NTHR, 0, stream>>>(x, h0, bias_s, wihp, whhp, hb, flags, (float*)d_out);
}

// Round 5
// 8062.786 us; speedup vs baseline: 2.7498x; 1.0653x over previous
//
#include <hip/hip_runtime.h>
#include <stdint.h>

#define TSEQ 1024
#define BB   32
#define DD   512
#define HH   512
#define NTHR 384
#define GRID 256   // 256 blocks launched; the 32 sharing one XCD self-select

typedef __attribute__((ext_vector_type(8))) __bf16 bf16x8;
typedef __attribute__((ext_vector_type(8))) unsigned short us8;
typedef __attribute__((ext_vector_type(4))) float f32x4;
typedef __attribute__((ext_vector_type(2))) float f32x2;
typedef __attribute__((ext_vector_type(4))) int i32x4;
typedef __attribute__((ext_vector_type(2))) int i32x2;

union Frag8 { us8 u; bf16x8 b; };
union FragI { i32x4 i; bf16x8 b; };

__device__ __forceinline__ unsigned short f2bf(float f) {
  union { float f; unsigned u; } v; v.f = f;
  unsigned u = v.u;
  u += 0x7fffu + ((u >> 16) & 1u);   // RNE
  return (unsigned short)(u >> 16);
}
__device__ __forceinline__ float sigm(float x) { return 1.0f / (1.0f + __expf(-x)); }
__device__ __forceinline__ float tanh_fast(float x) { return 1.0f - 2.0f / (__expf(2.0f * x) + 1.0f); }
__device__ __forceinline__ float softplus_(float x) { return (x > 15.0f) ? x : log1pf(__expf(x)); }

// LDS-only barrier: no vmcnt(0) drain on the critical path.
__device__ __forceinline__ void ldsbar() {
  asm volatile("s_waitcnt lgkmcnt(0)\n\ts_barrier" ::: "memory");
}

// packed B-fragment layout: [g][n>>4 (col tile)][k>>5 (kiter)][lane][8]
__device__ __forceinline__ int packidx(int g, int n, int k) {
  return ((g * 32 + (n >> 4)) * 16 + (k >> 5)) * 512 +
         (((k >> 3) & 3) * 16 + (n & 15)) * 8 + (k & 7);
}
// packed h layout (A-fragment order)
__device__ __forceinline__ int hidx(int m, int k) {
  return (k >> 5) * 1024 + ((k >> 3) & 3) * 256 + m * 8 + (k & 7);
}

__global__ void sample_kernel(const float* __restrict__ wih_mu, const float* __restrict__ wih_rho,
                              const float* __restrict__ whh_mu, const float* __restrict__ whh_rho,
                              const float* __restrict__ b_mu, const float* __restrict__ b_rho,
                              const float* __restrict__ eps_ih, const float* __restrict__ eps_hh,
                              const float* __restrict__ eps_b, const float* __restrict__ h0,
                              float* __restrict__ bias_s, unsigned short* __restrict__ wihp,
                              unsigned short* __restrict__ whhp, unsigned short* __restrict__ hb) {
  int gid = blockIdx.x * 256 + threadIdx.x;
  if (gid >= 512 * 2048) return;
  int k = gid >> 11, col = gid & 2047;
  if (col < 1536) {
    float w = wih_mu[gid] + softplus_(wih_rho[gid]) * eps_ih[gid];
    wihp[packidx(col >> 9, col & 511, k)] = f2bf(w);
  }
  {
    int g = -1, n = 0;
    if (col < 1024) { g = col >> 9; n = col & 511; }
    else if (col >= 1536) { g = 2; n = col - 1536; }
    if (g >= 0) {
      float w = whh_mu[gid] + softplus_(whh_rho[gid]) * eps_hh[gid];
      whhp[packidx(g, n, k)] = f2bf(w);
    }
  }
  if (gid < 2048) bias_s[gid] = b_mu[gid] + softplus_(b_rho[gid]) * eps_b[gid];
  // h0 -> hb buffer 0 (end-of-kernel writeback -> visible everywhere)
  if (gid < BB * HH) {
    int m = gid >> 9, kk = gid & 511;
    hb[hidx(m, kk)] = f2bf(h0[gid]);
  }
}

// Persistent single-XCD scan. 256 blocks launch; each reads HW_REG_XCC_ID and the
// first XCD to register 32 blocks wins — those 32 blocks (one shared L2) run the
// recurrence, the rest exit. All h/flag exchange is intra-XCD: plain stores
// (write-through L1 -> shared L2) + sc0 loads (bypass stale CU L1, hit L2).
// Per-wave flags, monotone >= check; per-wave vmcnt(0) drain (~L2 ack) before flag.
__global__ __launch_bounds__(NTHR, 1) void gru_scan(
    const float* __restrict__ x, const float* __restrict__ h0,
    const float* __restrict__ bias_s,
    const unsigned short* __restrict__ wihp, const unsigned short* __restrict__ whhp,
    unsigned short* __restrict__ hb, int* __restrict__ cnt, int* __restrict__ winner,
    unsigned* __restrict__ flags4, float* __restrict__ out)
{
  __shared__ float Ar[2][32][17];
  __shared__ float Az[2][32][17];
  __shared__ float P1[2][32][17];  // xg n-part
  __shared__ float P2[2][32][17];  // rec n-part
  __shared__ int s_rank;

  const int tid = threadIdx.x;

  // ---- team formation: self-select 32 co-L2 blocks ----
  if (tid == 0) {
    int xcd;
    asm volatile("s_getreg_b32 %0, hwreg(HW_REG_XCC_ID)" : "=s"(xcd));
    xcd &= 7;
    int r = atomicAdd(&cnt[xcd], 1);
    if (r == 31) atomicCAS(winner, -1, xcd);   // 32nd registrant claims the win
    int w;
    while ((w = __hip_atomic_load(winner, __ATOMIC_RELAXED,
                                  __HIP_MEMORY_SCOPE_AGENT)) == -1)
      __builtin_amdgcn_s_sleep(2);
    s_rank = (w == xcd && r < 32) ? r : -1;
  }
  __syncthreads();
  const int rank = s_rank;
  if (rank < 0) return;   // 224 blocks exit; 32 same-XCD blocks continue

  const int lane = tid & 63;
  const int wave = tid >> 6;      // 0..5
  const int g = wave >> 1;        // gate 0=r 1=z 2=n
  const int mh = wave & 1;        // m half
  const int l15 = lane & 15;
  const int lq = lane >> 4;       // k-group (A/B) == row quad (C/D)
  const int c0 = rank * 16;

  // epilogue mapping: 256 threads, each handles (m, 2 adjacent cols)
  const int em = tid >> 3;
  const int ejp = (tid & 7) * 2;
  const bool active = tid < 256;
  float b_r[2], b_z[2], b_n[2], b_hn[2], hold[2];
  if (active) {
#pragma unroll
    for (int e = 0; e < 2; e++) {
      int k = c0 + ejp + e;
      b_r[e]  = bias_s[k];
      b_z[e]  = bias_s[512 + k];
      b_n[e]  = bias_s[1024 + k];
      b_hn[e] = bias_s[1536 + k];
      hold[e] = h0[em * HH + k];
    }
  }

  // preload W_hh B-fragments (64 VGPRs, resident for whole kernel)
  Frag8 wreg[16];
  {
    const unsigned short* wb = whhp + (size_t)((g * 32 + rank) * 16) * 512 + lane * 8;
#pragma unroll
    for (int ki = 0; ki < 16; ki++) wreg[ki].u = *(const us8*)(wb + ki * 512);
  }

  const unsigned short* wib = wihp + (size_t)((g * 32 + rank) * 16) * 512 + lane * 8;
  const int xrow = mh * 16 + l15;

  f32x4 xcur;
  { // prologue: xg for t=0
    f32x4 a0 = {0.f, 0.f, 0.f, 0.f}, a1 = {0.f, 0.f, 0.f, 0.f};
    const float* xs = x + (size_t)xrow * TSEQ * DD + lq * 8;
#pragma unroll
    for (int ki = 0; ki < 16; ki++) {
      f32x4 x0 = *(const f32x4*)(xs + ki * 32);
      f32x4 x1 = *(const f32x4*)(xs + ki * 32 + 4);
      Frag8 a;
#pragma unroll
      for (int j = 0; j < 4; j++) { a.u[j] = f2bf(x0[j]); a.u[4 + j] = f2bf(x1[j]); }
      Frag8 b; b.u = *(const us8*)(wib + ki * 512);
      if (ki & 1) a1 = __builtin_amdgcn_mfma_f32_16x16x32_bf16(a.b, b.b, a1, 0, 0, 0);
      else        a0 = __builtin_amdgcn_mfma_f32_16x16x32_bf16(a.b, b.b, a0, 0, 0, 0);
    }
    xcur = a0 + a1;
  }

  for (int t = 0; t < TSEQ; t++) {
    // ---- phase 0: every wave polls all 128 wave-flags (>= t, monotone) ----
    if (t > 0) {
      const unsigned tgt = (unsigned)t;
      for (;;) {
        i32x2 f;
        asm volatile("global_load_dwordx2 %0, %1, off sc0"
                     : "=&v"(f) : "v"(flags4 + 2 * lane));
        asm volatile("s_waitcnt vmcnt(0)" : "+v"(f) :: "memory");
        if (__all(((unsigned)f[0] >= tgt) && ((unsigned)f[1] >= tgt))) break;
        __builtin_amdgcn_s_sleep(1);
      }
    }

    // ---- phase 1: A-fragments via sc0 loads from the shared L2 ----
    FragI af[16];
    {
      const unsigned short* src = hb + (t & 1) * 16384 + lq * 256 + (mh * 16 + l15) * 8;
#pragma unroll
      for (int ki = 0; ki < 16; ki++)
        asm volatile("global_load_dwordx4 %0, %1, off sc0"
                     : "=&v"(af[ki].i) : "v"(src + ki * 1024));
      asm volatile("s_waitcnt vmcnt(0)"
                   : "+v"(af[0].i), "+v"(af[1].i), "+v"(af[2].i), "+v"(af[3].i),
                     "+v"(af[4].i), "+v"(af[5].i), "+v"(af[6].i), "+v"(af[7].i),
                     "+v"(af[8].i), "+v"(af[9].i), "+v"(af[10].i), "+v"(af[11].i),
                     "+v"(af[12].i), "+v"(af[13].i), "+v"(af[14].i), "+v"(af[15].i)
                   :
                   : "memory");
    }
    f32x4 rec0 = {0.f, 0.f, 0.f, 0.f}, rec1 = {0.f, 0.f, 0.f, 0.f};
#pragma unroll
    for (int ki = 0; ki < 8; ki++) {
      rec0 = __builtin_amdgcn_mfma_f32_16x16x32_bf16(af[ki].b,     wreg[ki].b,     rec0, 0, 0, 0);
      rec1 = __builtin_amdgcn_mfma_f32_16x16x32_bf16(af[ki + 8].b, wreg[ki + 8].b, rec1, 0, 0, 0);
    }
    f32x4 rec = rec0 + rec1;

    // ---- phase 2: publish pre-activations (LDS double-buffered by t&1) ----
    const int pb = t & 1;
#pragma unroll
    for (int r = 0; r < 4; r++) {
      int m = mh * 16 + lq * 4 + r;
      if (g == 0)      Ar[pb][m][l15] = xcur[r] + rec[r];
      else if (g == 1) Az[pb][m][l15] = xcur[r] + rec[r];
      else             { P1[pb][m][l15] = xcur[r]; P2[pb][m][l15] = rec[r]; }
    }
    ldsbar();   // the ONLY block barrier per step (LDS dbuf covers reuse)

    // ---- phase 3: gates + state update; intra-XCD release: stores -> drain -> flag ----
    if (active) {
      float hn[2];
#pragma unroll
      for (int e = 0; e < 2; e++) {
        int j = ejp + e;
        float r1 = sigm(Ar[pb][em][j] + b_r[e]);
        float z1 = sigm(Az[pb][em][j] + b_z[e]);
        float n1 = tanh_fast(P1[pb][em][j] + b_n[e] + r1 * (P2[pb][em][j] + b_hn[e]));
        hn[e] = (1.f - z1) * n1 + z1 * hold[e];
        hold[e] = hn[e];
      }
      unsigned short* hbdst = hb + ((t + 1) & 1) * 16384;
      unsigned packed = (unsigned)f2bf(hn[0]) | ((unsigned)f2bf(hn[1]) << 16);
      __hip_atomic_store((unsigned*)(hbdst + hidx(em, c0 + ejp)), packed,
                         __ATOMIC_RELAXED, __HIP_MEMORY_SCOPE_WORKGROUP);  // plain store -> shared L2
      asm volatile("s_waitcnt vmcnt(0)" ::: "memory");   // L2 ack (~300 cy), wave-local
      if (lane == 0)
        __hip_atomic_store(&flags4[rank * 4 + wave], (unsigned)(t + 1),
                           __ATOMIC_RELAXED, __HIP_MEMORY_SCOPE_WORKGROUP);
      // out stores off the release path
      int k0 = c0 + ejp;
      f32x2 ov; ov[0] = hn[0]; ov[1] = hn[1];
      *(f32x2*)(out + (size_t)em * (TSEQ * HH) + (size_t)t * HH + k0) = ov;
      if (t == TSEQ - 1)
        *(f32x2*)(out + (size_t)BB * TSEQ * HH + em * HH + k0) = ov;
    }

    // ---- phase 4: xg(t+1), overlapped with flag propagation ----
    if (t + 1 < TSEQ) {
      f32x4 a0 = {0.f, 0.f, 0.f, 0.f}, a1 = {0.f, 0.f, 0.f, 0.f};
      const float* xs = x + ((size_t)xrow * TSEQ + (t + 1)) * DD + lq * 8;
#pragma unroll
      for (int ki = 0; ki < 16; ki++) {
        f32x4 x0 = *(const f32x4*)(xs + ki * 32);
        f32x4 x1 = *(const f32x4*)(xs + ki * 32 + 4);
        Frag8 a;
#pragma unroll
        for (int j = 0; j < 4; j++) { a.u[j] = f2bf(x0[j]); a.u[4 + j] = f2bf(x1[j]); }
        Frag8 b; b.u = *(const us8*)(wib + ki * 512);
        if (ki & 1) a1 = __builtin_amdgcn_mfma_f32_16x16x32_bf16(a.b, b.b, a1, 0, 0, 0);
        else        a0 = __builtin_amdgcn_mfma_f32_16x16x32_bf16(a.b, b.b, a0, 0, 0, 0);
      }
      xcur = a0 + a1;
    }
  }
}

extern "C" void kernel_launch(void* const* d_in, const int* in_sizes, int n_in,
                              void* d_out, int out_size, void* d_ws, size_t ws_size,
                              hipStream_t stream) {
  const float* x       = (const float*)d_in[0];
  const float* h0      = (const float*)d_in[1];
  const float* wih_mu  = (const float*)d_in[2];
  const float* wih_rho = (const float*)d_in[3];
  const float* whh_mu  = (const float*)d_in[4];
  const float* whh_rho = (const float*)d_in[5];
  const float* b_mu    = (const float*)d_in[6];
  const float* b_rho   = (const float*)d_in[7];
  const float* eps_ih  = (const float*)d_in[8];
  const float* eps_hh  = (const float*)d_in[9];
  const float* eps_b   = (const float*)d_in[10];

  uint8_t* ws = (uint8_t*)d_ws;
  int* cnt              = (int*)ws;                                   // 8 ints
  int* winner           = (int*)(ws + 64);                            // 1 int
  unsigned* flags4      = (unsigned*)(ws + 128);                      // 128 uints
  float* bias_s         = (float*)(ws + 4096);                        // 8KB
  unsigned short* wihp  = (unsigned short*)(ws + 16384);              // 1.5MB
  unsigned short* whhp  = (unsigned short*)(ws + 16384 + (1u << 21)); // 1.5MB
  unsigned short* hb    = (unsigned short*)(ws + 16384 + (2u << 21)); // 2 x 32KB

  hipMemsetAsync(ws, 0, 1024, stream);          // cnt + flags = 0
  hipMemsetAsync(ws + 64, 0xFF, 4, stream);     // winner = -1
  sample_kernel<<<4096, 256, 0, stream>>>(wih_mu, wih_rho, whh_mu, whh_rho,
                                          b_mu, b_rho, eps_ih, eps_hh, eps_b, h0,
                                          bias_s, wihp, whhp, hb);
  gru_scan<<<GRID, NTHR, 0, stream>>>(x, h0, bias_s, wihp, whhp, hb,
                                      cnt, winner, flags4, (float*)d_out);
}